// Round 3
// baseline (959.398 us; speedup 1.0000x reference)
//
#include <hip/hip_runtime.h>
#include <math.h>

// Problem constants (fixed by setup_inputs)
constexpr int B_   = 2;
constexpr int C_   = 64;
constexpr int H_   = 128;
constexpr int W_   = 128;
constexpr int HW_  = H_ * W_;
constexpr int DG_  = 16;   // deformable groups
constexpr int KK_  = 9;    // 3x3 taps
constexpr int CG_  = 4;    // channels per group = C/DG
constexpr int OFFC_ = 3 * KK_ * DG_;  // 432

// ---------------------------------------------------------------------------
// Weight transpose: in[OC][IC9] -> out[IC9][OC]  (OC contiguous -> one
// s_load_dwordx16 per 16-chan chunk instead of 16 strided s_load_dword).
// ---------------------------------------------------------------------------
template <int OC, int IC9>
__global__ __launch_bounds__(256) void transpose_w_k(
    const float* __restrict__ in, float* __restrict__ out)
{
    const int j = blockIdx.x * 256 + threadIdx.x;
    if (j >= OC * IC9) return;
    const int row = j / OC;   // ic*9 + tap
    const int col = j - row * OC;
    out[j] = in[(size_t)col * IC9 + row];
}

// ---------------------------------------------------------------------------
// Zero-init d_out (harness poisons it to 0xAA; deform accumulates atomically).
// ---------------------------------------------------------------------------
__global__ __launch_bounds__(256) void zero_k(float4* __restrict__ p, int n4)
{
    const int i = blockIdx.x * 256 + threadIdx.x;
    if (i < n4) p[i] = make_float4(0.f, 0.f, 0.f, 0.f);
}

// ---------------------------------------------------------------------------
// Direct 3x3 conv, pad=1. Thread: PX pixels x 16 out chans.
// ---------------------------------------------------------------------------
template <int CIN, int COUT, int PX>
__global__ __launch_bounds__(256) void conv3x3_leaky_k(
    const float* __restrict__ in, const float* __restrict__ wt,
    const float* __restrict__ bias, float* __restrict__ out)
{
    const int xp = blockIdx.x * 16 + threadIdx.x;
    const int yb = (blockIdx.y * 16 + threadIdx.y) * PX;
    const int z  = blockIdx.z;
    constexpr int NCHUNK = COUT / 16;
    const int b   = z / NCHUNK;
    const int ocb = (z % NCHUNK) * 16;

    float acc[PX][16];
#pragma unroll
    for (int p = 0; p < PX; ++p)
#pragma unroll
        for (int o = 0; o < 16; ++o) acc[p][o] = bias[ocb + o];

    const bool vxm = (xp - 1 >= 0);
    const bool vxp = (xp + 1 < W_);
    bool vr[PX + 2];
#pragma unroll
    for (int r = 0; r < PX + 2; ++r)
        vr[r] = ((unsigned)(yb + r - 1) < (unsigned)H_);

    const float* inb = in + (size_t)b * CIN * HW_;
    for (int ic = 0; ic < CIN; ++ic) {
        const float* inc = inb + (size_t)ic * HW_;
        float rv[PX + 2][3];
#pragma unroll
        for (int r = 0; r < PX + 2; ++r) {
            const int yy = yb + r - 1;
            const float* rowp = inc + yy * W_ + xp;
            rv[r][0] = (vr[r] && vxm) ? rowp[-1] : 0.f;
            rv[r][1] = vr[r] ? rowp[0] : 0.f;
            rv[r][2] = (vr[r] && vxp) ? rowp[1] : 0.f;
        }
        const float* wrow = wt + (size_t)(ic * 9) * COUT + ocb;
#pragma unroll
        for (int t = 0; t < 9; ++t) {
            float wv[16];
#pragma unroll
            for (int o = 0; o < 16; ++o) wv[o] = wrow[(size_t)t * COUT + o];
#pragma unroll
            for (int p = 0; p < PX; ++p) {
                const float v = rv[p + t / 3][t % 3];
#pragma unroll
                for (int o = 0; o < 16; ++o)
                    acc[p][o] = fmaf(v, wv[o], acc[p][o]);
            }
        }
    }

#pragma unroll
    for (int p = 0; p < PX; ++p) {
        const int pix = (yb + p) * W_ + xp;
#pragma unroll
        for (int o = 0; o < 16; ++o) {
            float r = acc[p][o];
            r = (r >= 0.f) ? r : 0.1f * r;
            out[((size_t)(b * COUT + ocb + o)) * HW_ + pix] = r;
        }
    }
}

// ---------------------------------------------------------------------------
// Conv3 (64 -> 432) with fused offset/mask epilogue, PX pixels/thread.
// omap[b][g*9+k][slot][H][W], slot 0=off_y 1=off_x 2=mask.
// ---------------------------------------------------------------------------
template <int PX>
__global__ __launch_bounds__(256) void conv3_off_k(
    const float* __restrict__ in, const float* __restrict__ wt,
    const float* __restrict__ bias, const float* __restrict__ flow,
    float* __restrict__ omap)
{
    const int xp = blockIdx.x * 16 + threadIdx.x;
    const int yb = (blockIdx.y * 16 + threadIdx.y) * PX;
    const int z  = blockIdx.z;
    constexpr int CIN = 64;
    constexpr int COUT = OFFC_;
    constexpr int NCHUNK = COUT / 16;   // 27
    const int b   = z / NCHUNK;
    const int ocb = (z % NCHUNK) * 16;

    float acc[PX][16];
#pragma unroll
    for (int p = 0; p < PX; ++p)
#pragma unroll
        for (int o = 0; o < 16; ++o) acc[p][o] = bias[ocb + o];

    const bool vxm = (xp - 1 >= 0);
    const bool vxp = (xp + 1 < W_);
    bool vr[PX + 2];
#pragma unroll
    for (int r = 0; r < PX + 2; ++r)
        vr[r] = ((unsigned)(yb + r - 1) < (unsigned)H_);

    const float* inb = in + (size_t)b * CIN * HW_;
    for (int ic = 0; ic < CIN; ++ic) {
        const float* inc = inb + (size_t)ic * HW_;
        float rv[PX + 2][3];
#pragma unroll
        for (int r = 0; r < PX + 2; ++r) {
            const int yy = yb + r - 1;
            const float* rowp = inc + yy * W_ + xp;
            rv[r][0] = (vr[r] && vxm) ? rowp[-1] : 0.f;
            rv[r][1] = vr[r] ? rowp[0] : 0.f;
            rv[r][2] = (vr[r] && vxp) ? rowp[1] : 0.f;
        }
        const float* wrow = wt + (size_t)(ic * 9) * COUT + ocb;
#pragma unroll
        for (int t = 0; t < 9; ++t) {
            float wv[16];
#pragma unroll
            for (int o = 0; o < 16; ++o) wv[o] = wrow[(size_t)t * COUT + o];
#pragma unroll
            for (int p = 0; p < PX; ++p) {
                const float v = rv[p + t / 3][t % 3];
#pragma unroll
                for (int o = 0; o < 16; ++o)
                    acc[p][o] = fmaf(v, wv[o], acc[p][o]);
            }
        }
    }

#pragma unroll
    for (int p = 0; p < PX; ++p) {
        const int pix = (yb + p) * W_ + xp;
#pragma unroll
        for (int o = 0; o < 16; ++o) {
            const int oc = ocb + o;
            float val = acc[p][o];
            int g, k, slot;
            if (oc < 2 * DG_ * KK_) {          // offset channels (0..287)
                g = oc / 18;
                const int rem = oc - g * 18;
                k = rem >> 1;
                slot = rem & 1;                 // 0 = y, 1 = x
                const float fl = flow[(size_t)(b * 2 + (1 - slot)) * HW_ + pix];
                val = 10.f * tanhf(val) + fl;
            } else {                            // mask channels (288..431)
                const int c = oc - 2 * DG_ * KK_;
                g = c / 9;
                k = c - g * 9;
                slot = 2;
                val = 1.f / (1.f + expf(-val));
            }
            omap[((size_t)((b * DG_ * KK_ + g * KK_ + k) * 3 + slot)) * HW_ + pix] = val;
        }
    }
}

// ---------------------------------------------------------------------------
// Deformable gather + einsum, g-sliced for occupancy.
// Thread = (pixel, 16-oc chunk, slice of 4 groups); accumulates into d_out
// via fp32 atomicAdd (4 contributions/element). Grid z = B * 4 * 4 = 32
// -> 2048 blocks -> 32 waves/CU (vs 8 before): hides scattered-gather latency.
// ---------------------------------------------------------------------------
__global__ __launch_bounds__(256) void deform_k(
    const float* __restrict__ x, const float* __restrict__ omap,
    const float* __restrict__ wkT, float* __restrict__ out)
{
    const int xp = blockIdx.x * 16 + threadIdx.x;
    const int yp = blockIdx.y * 16 + threadIdx.y;
    const int z  = blockIdx.z;             // b(2) x ocb(4) x slice(4)
    const int b   = z >> 4;
    const int ocb = ((z >> 2) & 3) * 16;
    const int g0  = (z & 3) * 4;

    float acc[16];
#pragma unroll
    for (int o = 0; o < 16; ++o) acc[o] = 0.f;

    const float* xb = x + (size_t)b * C_ * HW_;
    const int pix = yp * W_ + xp;

#pragma unroll
    for (int gi = 0; gi < 4; ++gi) {
        const int g = g0 + gi;
#pragma unroll
        for (int k = 0; k < KK_; ++k) {
            const size_t obase = ((size_t)((b * DG_ * KK_ + g * KK_ + k) * 3)) * HW_ + pix;
            const float oy = omap[obase];
            const float ox = omap[obase + HW_];
            const float m  = omap[obase + 2 * HW_];

            const float py = (float)(yp + (k / 3) - 1) + oy;
            const float px = (float)(xp + (k % 3) - 1) + ox;
            const float y0f = floorf(py);
            const float x0f = floorf(px);
            const float wy = py - y0f;
            const float wx = px - x0f;
            const int y0 = (int)y0f, x0 = (int)x0f;
            const int y1 = y0 + 1,  x1 = x0 + 1;
            const bool vy0 = ((unsigned)y0 < (unsigned)H_);
            const bool vy1 = ((unsigned)y1 < (unsigned)H_);
            const bool vx0 = ((unsigned)x0 < (unsigned)W_);
            const bool vx1 = ((unsigned)x1 < (unsigned)W_);
            const float w00 = (1.f - wy) * (1.f - wx);
            const float w01 = (1.f - wy) * wx;
            const float w10 = wy * (1.f - wx);
            const float w11 = wy * wx;

#pragma unroll
            for (int c = 0; c < CG_; ++c) {
                const float* img = xb + (size_t)(g * CG_ + c) * HW_;
                float v = 0.f;
                if (vy0 && vx0) v = fmaf(w00, img[y0 * W_ + x0], v);
                if (vy0 && vx1) v = fmaf(w01, img[y0 * W_ + x1], v);
                if (vy1 && vx0) v = fmaf(w10, img[y1 * W_ + x0], v);
                if (vy1 && vx1) v = fmaf(w11, img[y1 * W_ + x1], v);
                const float s = v * m;
                const float* wp = wkT + (size_t)((g * CG_ + c) * 9 + k) * C_ + ocb;
                float wv[16];
#pragma unroll
                for (int o = 0; o < 16; ++o) wv[o] = wp[o];
#pragma unroll
                for (int o = 0; o < 16; ++o)
                    acc[o] = fmaf(s, wv[o], acc[o]);
            }
        }
    }

#pragma unroll
    for (int o = 0; o < 16; ++o)
        atomicAdd(&out[((size_t)(b * C_ + ocb + o)) * HW_ + pix], acc[o]);
}

// ---------------------------------------------------------------------------
extern "C" void kernel_launch(void* const* d_in, const int* in_sizes, int n_in,
                              void* d_out, int out_size, void* d_ws, size_t ws_size,
                              hipStream_t stream)
{
    const float* x    = (const float*)d_in[0];
    const float* ef   = (const float*)d_in[1];
    const float* flow = (const float*)d_in[2];
    const float* w1   = (const float*)d_in[3];
    const float* b1   = (const float*)d_in[4];
    const float* w2   = (const float*)d_in[5];
    const float* b2   = (const float*)d_in[6];
    const float* w3   = (const float*)d_in[7];
    const float* b3   = (const float*)d_in[8];
    const float* wk   = (const float*)d_in[9];
    float* out = (float*)d_out;

    // Workspace layout (floats): h1 8.4MB | h2 8.4MB | om 56.6MB | wt* 1.6MB
    float* h1  = (float*)d_ws;
    float* h2  = h1 + (size_t)B_ * C_ * HW_;
    float* om  = h2 + (size_t)B_ * C_ * HW_;
    float* wt1 = om + (size_t)B_ * OFFC_ * HW_;
    float* wt2 = wt1 + 1152 * 64;
    float* wt3 = wt2 + 576 * 64;
    float* wkT = wt3 + 576 * 432;

    transpose_w_k<64, 1152><<<dim3((64 * 1152 + 255) / 256), 256, 0, stream>>>(w1, wt1);
    transpose_w_k<64, 576><<<dim3((64 * 576 + 255) / 256), 256, 0, stream>>>(w2, wt2);
    transpose_w_k<432, 576><<<dim3((432 * 576 + 255) / 256), 256, 0, stream>>>(w3, wt3);
    transpose_w_k<64, 576><<<dim3((64 * 576 + 255) / 256), 256, 0, stream>>>(wk, wkT);
    zero_k<<<dim3((B_ * C_ * HW_ / 4 + 255) / 256), 256, 0, stream>>>((float4*)out, B_ * C_ * HW_ / 4);

    dim3 blk(16, 16, 1);
    conv3x3_leaky_k<2 * C_, C_, 1><<<dim3(W_ / 16, H_ / 16, B_ * (C_ / 16)), blk, 0, stream>>>(ef, wt1, b1, h1);
    conv3x3_leaky_k<C_, C_, 1><<<dim3(W_ / 16, H_ / 16, B_ * (C_ / 16)), blk, 0, stream>>>(h1, wt2, b2, h2);
    conv3_off_k<2><<<dim3(W_ / 16, H_ / 32, B_ * (OFFC_ / 16)), blk, 0, stream>>>(h2, wt3, b3, flow, om);
    deform_k<<<dim3(W_ / 16, H_ / 16, B_ * 16), blk, 0, stream>>>(x, om, wkT, out);
}

// Round 4
// 557.644 us; speedup vs baseline: 1.7204x; 1.7204x over previous
//
#include <hip/hip_runtime.h>
#include <math.h>

// Problem constants (fixed by setup_inputs)
constexpr int B_   = 2;
constexpr int C_   = 64;
constexpr int H_   = 128;
constexpr int W_   = 128;
constexpr int HW_  = H_ * W_;
constexpr int DG_  = 16;   // deformable groups
constexpr int KK_  = 9;    // 3x3 taps
constexpr int CG_  = 4;    // channels per group = C/DG
constexpr int OFFC_ = 3 * KK_ * DG_;  // 432
constexpr int R_   = C_ * KK_;        // 576 reduction length of final einsum

// ---------------------------------------------------------------------------
// Weight transpose: in[OC][IC9] -> out[IC9][OC]  (OC contiguous -> one
// s_load_dwordx16 per 16-chan chunk instead of 16 strided s_load_dword).
// ---------------------------------------------------------------------------
template <int OC, int IC9>
__global__ __launch_bounds__(256) void transpose_w_k(
    const float* __restrict__ in, float* __restrict__ out)
{
    const int j = blockIdx.x * 256 + threadIdx.x;
    if (j >= OC * IC9) return;
    const int row = j / OC;   // ic*9 + tap
    const int col = j - row * OC;
    out[j] = in[(size_t)col * IC9 + row];
}

// ---------------------------------------------------------------------------
// Direct 3x3 conv, pad=1. Thread: PX pixels x 16 out chans.
// ---------------------------------------------------------------------------
template <int CIN, int COUT, int PX>
__global__ __launch_bounds__(256) void conv3x3_leaky_k(
    const float* __restrict__ in, const float* __restrict__ wt,
    const float* __restrict__ bias, float* __restrict__ out)
{
    const int xp = blockIdx.x * 16 + threadIdx.x;
    const int yb = (blockIdx.y * 16 + threadIdx.y) * PX;
    const int z  = blockIdx.z;
    constexpr int NCHUNK = COUT / 16;
    const int b   = z / NCHUNK;
    const int ocb = (z % NCHUNK) * 16;

    float acc[PX][16];
#pragma unroll
    for (int p = 0; p < PX; ++p)
#pragma unroll
        for (int o = 0; o < 16; ++o) acc[p][o] = bias[ocb + o];

    const bool vxm = (xp - 1 >= 0);
    const bool vxp = (xp + 1 < W_);
    bool vr[PX + 2];
#pragma unroll
    for (int r = 0; r < PX + 2; ++r)
        vr[r] = ((unsigned)(yb + r - 1) < (unsigned)H_);

    const float* inb = in + (size_t)b * CIN * HW_;
    for (int ic = 0; ic < CIN; ++ic) {
        const float* inc = inb + (size_t)ic * HW_;
        float rv[PX + 2][3];
#pragma unroll
        for (int r = 0; r < PX + 2; ++r) {
            const int yy = yb + r - 1;
            const float* rowp = inc + yy * W_ + xp;
            rv[r][0] = (vr[r] && vxm) ? rowp[-1] : 0.f;
            rv[r][1] = vr[r] ? rowp[0] : 0.f;
            rv[r][2] = (vr[r] && vxp) ? rowp[1] : 0.f;
        }
        const float* wrow = wt + (size_t)(ic * 9) * COUT + ocb;
#pragma unroll
        for (int t = 0; t < 9; ++t) {
            float wv[16];
#pragma unroll
            for (int o = 0; o < 16; ++o) wv[o] = wrow[(size_t)t * COUT + o];
#pragma unroll
            for (int p = 0; p < PX; ++p) {
                const float v = rv[p + t / 3][t % 3];
#pragma unroll
                for (int o = 0; o < 16; ++o)
                    acc[p][o] = fmaf(v, wv[o], acc[p][o]);
            }
        }
    }

#pragma unroll
    for (int p = 0; p < PX; ++p) {
        const int pix = (yb + p) * W_ + xp;
#pragma unroll
        for (int o = 0; o < 16; ++o) {
            float r = acc[p][o];
            r = (r >= 0.f) ? r : 0.1f * r;
            out[((size_t)(b * COUT + ocb + o)) * HW_ + pix] = r;
        }
    }
}

// ---------------------------------------------------------------------------
// Conv3 (64 -> 432) with fused offset/mask epilogue, PX pixels/thread.
// omap[b][g*9+k][slot][H][W], slot 0=off_y 1=off_x 2=mask.
// ---------------------------------------------------------------------------
template <int PX>
__global__ __launch_bounds__(256) void conv3_off_k(
    const float* __restrict__ in, const float* __restrict__ wt,
    const float* __restrict__ bias, const float* __restrict__ flow,
    float* __restrict__ omap)
{
    const int xp = blockIdx.x * 16 + threadIdx.x;
    const int yb = (blockIdx.y * 16 + threadIdx.y) * PX;
    const int z  = blockIdx.z;
    constexpr int CIN = 64;
    constexpr int COUT = OFFC_;
    constexpr int NCHUNK = COUT / 16;   // 27
    const int b   = z / NCHUNK;
    const int ocb = (z % NCHUNK) * 16;

    float acc[PX][16];
#pragma unroll
    for (int p = 0; p < PX; ++p)
#pragma unroll
        for (int o = 0; o < 16; ++o) acc[p][o] = bias[ocb + o];

    const bool vxm = (xp - 1 >= 0);
    const bool vxp = (xp + 1 < W_);
    bool vr[PX + 2];
#pragma unroll
    for (int r = 0; r < PX + 2; ++r)
        vr[r] = ((unsigned)(yb + r - 1) < (unsigned)H_);

    const float* inb = in + (size_t)b * CIN * HW_;
    for (int ic = 0; ic < CIN; ++ic) {
        const float* inc = inb + (size_t)ic * HW_;
        float rv[PX + 2][3];
#pragma unroll
        for (int r = 0; r < PX + 2; ++r) {
            const int yy = yb + r - 1;
            const float* rowp = inc + yy * W_ + xp;
            rv[r][0] = (vr[r] && vxm) ? rowp[-1] : 0.f;
            rv[r][1] = vr[r] ? rowp[0] : 0.f;
            rv[r][2] = (vr[r] && vxp) ? rowp[1] : 0.f;
        }
        const float* wrow = wt + (size_t)(ic * 9) * COUT + ocb;
#pragma unroll
        for (int t = 0; t < 9; ++t) {
            float wv[16];
#pragma unroll
            for (int o = 0; o < 16; ++o) wv[o] = wrow[(size_t)t * COUT + o];
#pragma unroll
            for (int p = 0; p < PX; ++p) {
                const float v = rv[p + t / 3][t % 3];
#pragma unroll
                for (int o = 0; o < 16; ++o)
                    acc[p][o] = fmaf(v, wv[o], acc[p][o]);
            }
        }
    }

#pragma unroll
    for (int p = 0; p < PX; ++p) {
        const int pix = (yb + p) * W_ + xp;
#pragma unroll
        for (int o = 0; o < 16; ++o) {
            const int oc = ocb + o;
            float val = acc[p][o];
            int g, k, slot;
            if (oc < 2 * DG_ * KK_) {          // offset channels (0..287)
                g = oc / 18;
                const int rem = oc - g * 18;
                k = rem >> 1;
                slot = rem & 1;                 // 0 = y, 1 = x
                const float fl = flow[(size_t)(b * 2 + (1 - slot)) * HW_ + pix];
                val = 10.f * tanhf(val) + fl;
            } else {                            // mask channels (288..431)
                const int c = oc - 2 * DG_ * KK_;
                g = c / 9;
                k = c - g * 9;
                slot = 2;
                val = 1.f / (1.f + expf(-val));
            }
            omap[((size_t)((b * DG_ * KK_ + g * KK_ + k) * 3 + slot)) * HW_ + pix] = val;
        }
    }
}

// ---------------------------------------------------------------------------
// Phase A: bilinear gather. Thread = (pixel, one (g,k) tap). Tiny VGPR state,
// 18432 blocks -> full occupancy; every gather computed exactly once.
// val[b][(g*4+c)*9 + k][pix] = masked bilinear sample.
// ---------------------------------------------------------------------------
__global__ __launch_bounds__(256) void gather_k(
    const float* __restrict__ x, const float* __restrict__ omap,
    float* __restrict__ val)
{
    const int pix = blockIdx.x * 256 + threadIdx.x;
    const int z   = blockIdx.y;               // b * 144 + g*9 + k
    const int b   = z / (DG_ * KK_);
    const int gk  = z - b * DG_ * KK_;
    const int g   = gk / KK_;
    const int k   = gk - g * KK_;
    const int yp  = pix >> 7;
    const int xp  = pix & (W_ - 1);

    const size_t obase = ((size_t)(b * DG_ * KK_ + gk) * 3) * HW_ + pix;
    const float oy = omap[obase];
    const float ox = omap[obase + HW_];
    const float m  = omap[obase + 2 * HW_];

    const float py = (float)(yp + (k / 3) - 1) + oy;
    const float px = (float)(xp + (k % 3) - 1) + ox;
    const float y0f = floorf(py);
    const float x0f = floorf(px);
    const float wy = py - y0f;
    const float wx = px - x0f;
    const int y0 = (int)y0f, x0 = (int)x0f;
    const int y1 = y0 + 1,  x1 = x0 + 1;
    const bool vy0 = ((unsigned)y0 < (unsigned)H_);
    const bool vy1 = ((unsigned)y1 < (unsigned)H_);
    const bool vx0 = ((unsigned)x0 < (unsigned)W_);
    const bool vx1 = ((unsigned)x1 < (unsigned)W_);
    const float w00 = vy0 && vx0 ? (1.f - wy) * (1.f - wx) : 0.f;
    const float w01 = vy0 && vx1 ? (1.f - wy) * wx         : 0.f;
    const float w10 = vy1 && vx0 ? wy * (1.f - wx)         : 0.f;
    const float w11 = vy1 && vx1 ? wy * wx                 : 0.f;
    const int i00 = (vy0 && vx0) ? y0 * W_ + x0 : 0;
    const int i01 = (vy0 && vx1) ? y0 * W_ + x1 : 0;
    const int i10 = (vy1 && vx0) ? y1 * W_ + x0 : 0;
    const int i11 = (vy1 && vx1) ? y1 * W_ + x1 : 0;

    const float* xg = x + (size_t)(b * C_ + g * CG_) * HW_;
    float* vg = val + ((size_t)b * R_ + (size_t)(g * CG_) * KK_ + k) * HW_ + pix;
#pragma unroll
    for (int c = 0; c < CG_; ++c) {
        const float* img = xg + (size_t)c * HW_;
        float v = w00 * img[i00] + w01 * img[i01] + w10 * img[i10] + w11 * img[i11];
        vg[(size_t)c * KK_ * HW_] = v * m;
    }
}

// ---------------------------------------------------------------------------
// Phase B: dense einsum  out[b][o][pix] = sum_r val[b][r][pix] * wkT[r][o].
// Thread = (pixel, 16-oc chunk). Coalesced val loads, x16 scalar weights.
// ---------------------------------------------------------------------------
__global__ __launch_bounds__(256) void einsum_k(
    const float* __restrict__ val, const float* __restrict__ wkT,
    float* __restrict__ out)
{
    const int pix = blockIdx.x * 256 + threadIdx.x;
    const int z   = blockIdx.y;               // b(2) x ocb(4)
    const int b   = z >> 2;
    const int ocb = (z & 3) * 16;

    float acc[16];
#pragma unroll
    for (int o = 0; o < 16; ++o) acc[o] = 0.f;

    const float* vb = val + (size_t)b * R_ * HW_ + pix;
    const float* wp = wkT + ocb;
#pragma unroll 4
    for (int r = 0; r < R_; ++r) {
        const float s = vb[(size_t)r * HW_];
        const float* w = wp + (size_t)r * C_;
#pragma unroll
        for (int o = 0; o < 16; ++o)
            acc[o] = fmaf(s, w[o], acc[o]);
    }

#pragma unroll
    for (int o = 0; o < 16; ++o)
        out[((size_t)(b * C_ + ocb + o)) * HW_ + pix] = acc[o];
}

// ---------------------------------------------------------------------------
extern "C" void kernel_launch(void* const* d_in, const int* in_sizes, int n_in,
                              void* d_out, int out_size, void* d_ws, size_t ws_size,
                              hipStream_t stream)
{
    const float* x    = (const float*)d_in[0];
    const float* ef   = (const float*)d_in[1];
    const float* flow = (const float*)d_in[2];
    const float* w1   = (const float*)d_in[3];
    const float* b1   = (const float*)d_in[4];
    const float* w2   = (const float*)d_in[5];
    const float* b2   = (const float*)d_in[6];
    const float* w3   = (const float*)d_in[7];
    const float* b3   = (const float*)d_in[8];
    const float* wk   = (const float*)d_in[9];
    float* out = (float*)d_out;

    // Workspace layout (floats):
    //   h1:  B*64*HW    = 2,097,152   (8.4 MB)
    //   h2:  B*64*HW    = 2,097,152   (8.4 MB)
    //   om:  B*432*HW   = 14,155,776  (56.6 MB)
    //   val: B*576*HW   = 18,874,368  (75.5 MB)
    //   wt1/wt2/wt3/wkT ~ 0.4M        total ~150 MB
    float* h1  = (float*)d_ws;
    float* h2  = h1 + (size_t)B_ * C_ * HW_;
    float* om  = h2 + (size_t)B_ * C_ * HW_;
    float* val = om + (size_t)B_ * OFFC_ * HW_;
    float* wt1 = val + (size_t)B_ * R_ * HW_;
    float* wt2 = wt1 + 1152 * 64;
    float* wt3 = wt2 + 576 * 64;
    float* wkT = wt3 + 576 * 432;

    transpose_w_k<64, 1152><<<dim3((64 * 1152 + 255) / 256), 256, 0, stream>>>(w1, wt1);
    transpose_w_k<64, 576><<<dim3((64 * 576 + 255) / 256), 256, 0, stream>>>(w2, wt2);
    transpose_w_k<432, 576><<<dim3((432 * 576 + 255) / 256), 256, 0, stream>>>(w3, wt3);
    transpose_w_k<64, 576><<<dim3((64 * 576 + 255) / 256), 256, 0, stream>>>(wk, wkT);

    dim3 blk(16, 16, 1);
    conv3x3_leaky_k<2 * C_, C_, 1><<<dim3(W_ / 16, H_ / 16, B_ * (C_ / 16)), blk, 0, stream>>>(ef, wt1, b1, h1);
    conv3x3_leaky_k<C_, C_, 1><<<dim3(W_ / 16, H_ / 16, B_ * (C_ / 16)), blk, 0, stream>>>(h1, wt2, b2, h2);
    conv3_off_k<2><<<dim3(W_ / 16, H_ / 32, B_ * (OFFC_ / 16)), blk, 0, stream>>>(h2, wt3, b3, flow, om);

    gather_k<<<dim3(HW_ / 256, B_ * DG_ * KK_), 256, 0, stream>>>(x, om, val);
    einsum_k<<<dim3(HW_ / 256, B_ * 4), 256, 0, stream>>>(val, wkT, out);
}